// Round 20
// baseline (19708.200 us; speedup 1.0000x reference)
//
#include <hip/hip_runtime.h>
#include <hip/hip_bf16.h>
#include <stdint.h>
#include <math.h>

#define BB 16
#define QQ 1024
#define TT 512
#define FBIG 1e9f

// ---- XLA CPU f32 tanh (Eigen generic_fast_tanh_float / GenerateVF32Tanh):
// clamp +-7.99881172180175781, tiny-path |x|<0.0004 -> x, FMA-Horner rational
__device__ __forceinline__ float xla_tanhf(float x) {
    if (fabsf(x) < 0.0004f) return x;
    float t = fminf(fmaxf(x, -7.99881172180175781f), 7.99881172180175781f);
    float x2 = t * t;
    float p = fmaf(-2.76076847742355e-16f, x2, 2.00018790482477e-13f); // a13,a11
    p = fmaf(p, x2, -8.60467152213735e-11f);   // a9
    p = fmaf(p, x2, 5.12229709037114e-08f);    // a7
    p = fmaf(p, x2, 1.48572235717979e-05f);    // a5
    p = fmaf(p, x2, 6.37261928875436e-04f);    // a3
    p = fmaf(p, x2, 4.89352455891786e-03f);    // a1
    float num = t * p;
    float q = fmaf(1.19825839466702e-06f, x2, 1.18534705686654e-04f);  // b6,b4
    q = fmaf(q, x2, 2.26843463243900e-03f);    // b2
    q = fmaf(q, x2, 4.89352518554385e-03f);    // b0
    return num / q;
}

// XLA LogisticExpander: logistic(x) = 0.5 + 0.5*tanh(0.5*x)
__device__ __forceinline__ float xla_sigmoid(float x) {
    return 0.5f + 0.5f * xla_tanhf(0.5f * x);
}

// ---- XLA CPU f32 log (GenerateVF32Log, cephes): FMA-Horner, (p*x)*z tail,
// e*q1 / e*q2 fused, -0.5z as mul+sub; 2m-1 via (m-1)+m for small mantissa.
__device__ __forceinline__ float xla_logf(float y) {
    int ix = __float_as_int(y);
    int e = ((ix >> 23) & 0xff) - 126;
    float m = __int_as_float((ix & 0x007fffff) | 0x3f000000);   // [0.5,1)
    bool small = m < 0.707106781186547524f;
    float xm = m - 1.0f;
    if (small) { e -= 1; xm = xm + m; }     // tmp0 = (m-1) + m
    float z = xm * xm;
    float p = 7.0376836292E-2f;
    p = fmaf(p, xm, -1.1514610310E-1f);
    p = fmaf(p, xm, 1.1676998740E-1f);
    p = fmaf(p, xm, -1.2420140846E-1f);
    p = fmaf(p, xm, 1.4249322787E-1f);
    p = fmaf(p, xm, -1.6668057665E-1f);
    p = fmaf(p, xm, 2.0000714765E-1f);
    p = fmaf(p, xm, -2.4999993993E-1f);
    p = fmaf(p, xm, 3.3333331174E-1f);
    float yv = (p * xm) * z;                // (poly*x)*z
    float fe = (float)e;
    yv = fmaf(fe, -2.12194440e-4f, yv);     // y += e*q1
    yv = yv - 0.5f * z;                     // y -= 0.5*z (mul+sub)
    float res = xm + yv;
    res = fmaf(fe, 0.693359375f, res);      // x += e*q2
    return res;
}

// XLA-f32 focal diff: prob via tanh-logistic; **2.0 -> x*x; numpy/HLO order
__device__ __forceinline__ float xla_diff(float x) {
    float pr = xla_sigmoid(x);
    float s  = 1.0f - pr;
    float p2 = pr * pr;
    float s2 = s * s;
    float neg = (0.75f * p2) * (-xla_logf(s + 1e-8f));
    float pos = (0.25f * s2) * (-xla_logf(pr + 1e-8f));
    return pos - neg;
}

// ---- diff (focal class cost term per (b,q,c)) ----------------------------
__global__ void diff_kernel(const float* __restrict__ logits,
                            float* __restrict__ diff, int n) {
    int i = blockIdx.x * blockDim.x + threadIdx.x;
    if (i >= n) return;
    diff[i] = xla_diff(logits[i]);
}

// ---------------- cost matrix C[b][q][t] (t fastest, coalesced) -----------
__global__ void cost_kernel(const float* __restrict__ diff,
                            const float4* __restrict__ pp,
                            const float4* __restrict__ tp,
                            const int* __restrict__ labels,
                            float* __restrict__ Cout, int cls, size_t total) {
    size_t gid = (size_t)blockIdx.x * blockDim.x + threadIdx.x;
    if (gid >= total) return;
    int t = (int)(gid % TT);
    size_t bq = gid / TT;
    int q = (int)(bq % QQ);
    int b = (int)(bq / QQ);
    float4 P = pp[b * QQ + q];
    float4 G = tp[b * TT + t];
    float cp = ((fabsf(P.x - G.x) + fabsf(P.y - G.y)) + fabsf(P.z - G.z)) + fabsf(P.w - G.w);
    int lab = labels[b * TT + t];
    float cc = diff[(size_t)(b * QQ + q) * cls + lab];
    Cout[gid] = cc + cp;
}

// ---- fallback: cost with inline diff (no workspace needed) ---------------
__global__ void cost_inline_kernel(const float* __restrict__ logits,
                                   const float4* __restrict__ pp,
                                   const float4* __restrict__ tp,
                                   const int* __restrict__ labels,
                                   float* __restrict__ Cout, int cls, size_t total) {
    size_t gid = (size_t)blockIdx.x * blockDim.x + threadIdx.x;
    if (gid >= total) return;
    int t = (int)(gid % TT);
    size_t bq = gid / TT;
    int q = (int)(bq % QQ);
    int b = (int)(bq / QQ);
    float4 P = pp[b * QQ + q];
    float4 G = tp[b * TT + t];
    float cp = ((fabsf(P.x - G.x) + fabsf(P.y - G.y)) + fabsf(P.z - G.z)) + fabsf(P.w - G.w);
    int lab = labels[b * TT + t];
    float cc = xla_diff(logits[(size_t)(b * QQ + q) * cls + lab]);
    Cout[gid] = cc + cp;
}

// DPP-combine one reduction level of (value, meta) lexicographic min.
// Invalid-source lanes receive identity (2e9, 0xFFFFFFFF) via `old`.
#define DPP_STEP(CTRL)                                                        \
    {                                                                         \
        int s_v = __builtin_amdgcn_update_dpp(idv, bvI, (CTRL), 0xf, 0xf, false); \
        int s_m = __builtin_amdgcn_update_dpp(-1, (int)bmU, (CTRL), 0xf, 0xf, false); \
        float fs = __int_as_float(s_v);                                       \
        float fb = __int_as_float(bvI);                                       \
        bool bt = (fs < fb) || (fs == fb && (unsigned)s_m < bmU);             \
        bvI = bt ? s_v : bvI;                                                 \
        bmU = bt ? (unsigned)s_m : bmU;                                       \
    }

// lexicographic (value, meta) pairwise min
#define LEXMIN(av, am, bv2, bm2, ov, om)                                      \
    {                                                                         \
        bool t_ = ((bv2) < (av)) || (((bv2) == (av)) && ((bm2) < (am)));      \
        ov = t_ ? (bv2) : (av);                                               \
        om = t_ ? (bm2) : (am);                                               \
    }

// ---- LAP: r19 structure (passing) + ONE edit: lane-local argmin linear
// scan -> 4-level lexicographic (value, meta) tree. meta=(j<<10)|(p[j]+1)
// is strictly increasing in k, so lex-min == first-index-of-min: identical
// winner to the strict-< scan, ~95cy shorter dependency chain per step.
__global__ __launch_bounds__(64)
void lap_kernel(const float* __restrict__ logits,
                const float4* __restrict__ pp,
                const float4* __restrict__ tp,
                int cls,
                float* __restrict__ out) {
    __shared__ float u[TT];
    __shared__ float diff32[QQ];
    __shared__ float4 pps[QQ];
    __shared__ float4 tps[TT];
    __shared__ int p[QQ];
    __shared__ unsigned short way[QQ];

    int b = blockIdx.x;
    int lane = threadIdx.x;

    for (int j = lane; j < QQ; j += 64) {
        pps[j] = pp[b * QQ + j];
        diff32[j] = xla_diff(logits[(size_t)(b * QQ + j) * cls]);  // cls==1
        p[j] = -1;
    }
    for (int i = lane; i < TT; i += 64) {
        tps[i] = tp[b * TT + i];
        u[i] = 0.0f;
    }
    __syncthreads();

    // kernel-constant per-lane column data: LDS -> registers, once
    float dreg[16], px[16], py[16], pz[16], pw[16];
#pragma unroll
    for (int k = 0; k < 16; ++k) {
        dreg[k] = diff32[k * 64 + lane];
        float4 P = pps[k * 64 + lane];
        px[k] = P.x; py[k] = P.y; pz[k] = P.z; pw[k] = P.w;
    }

    float v[16];
#pragma unroll
    for (int k = 0; k < 16; ++k) v[k] = 0.0f;

    const int idv = __float_as_int(2e9f);

    for (int i = 0; i < TT; ++i) {
        unsigned used = 0;
        float minv[16], uacc[16];
        unsigned wayr[16];
        int p_cache[16];
        unsigned meta[16];
#pragma unroll
        for (int k = 0; k < 16; ++k) {
            minv[k] = FBIG;
            uacc[k] = 0.0f;
            wayr[k] = 0u;
            p_cache[k] = p[k * 64 + lane];          // phase-constant
            meta[k] = ((unsigned)(k * 64 + lane) << 10) | (unsigned)(p_cache[k] + 1);
        }
        int j0 = QQ;            // dummy column marker (== m)
        int jfree = -1;
        float ui0 = u[i];       // phase-start u of the new row
        float uu_i = ui0;       // running u[i] (dummy column's row)
        float4 G = tps[i];

        for (;;) {
            float gx = G.x, gy = G.y, gz = G.z, gw = G.w;
            // relax fresh columns: cur = ((cc + cp) - u[i0]) - v[j], all f32
#pragma unroll
            for (int k = 0; k < 16; ++k) {
                float cp = ((fabsf(px[k] - gx) + fabsf(py[k] - gy))
                            + fabsf(pz[k] - gz)) + fabsf(pw[k] - gw);
                float c = dreg[k] + cp;
                float cur = (c - ui0) - v[k];
                bool fresh = !((used >> k) & 1u);
                bool upd = fresh && (cur < minv[k]);
                minv[k] = upd ? cur : minv[k];
                wayr[k] = upd ? (unsigned)j0 : wayr[k];
            }
            // lane-local argmin: 4-level (value, meta) tree (the ONE edit)
            float dv[16];
#pragma unroll
            for (int k = 0; k < 16; ++k)
                dv[k] = ((used >> k) & 1u) ? FBIG : minv[k];
            float t8v[8]; unsigned t8m[8];
#pragma unroll
            for (int k = 0; k < 8; ++k)
                LEXMIN(dv[2*k], meta[2*k], dv[2*k+1], meta[2*k+1], t8v[k], t8m[k])
            float t4v[4]; unsigned t4m[4];
#pragma unroll
            for (int k = 0; k < 4; ++k)
                LEXMIN(t8v[2*k], t8m[2*k], t8v[2*k+1], t8m[2*k+1], t4v[k], t4m[k])
            float t2v[2]; unsigned t2m[2];
#pragma unroll
            for (int k = 0; k < 2; ++k)
                LEXMIN(t4v[2*k], t4m[2*k], t4v[2*k+1], t4m[2*k+1], t2v[k], t2m[k])
            float bv; unsigned bm;
            LEXMIN(t2v[0], t2m[0], t2v[1], t2m[1], bv, bm)
            // 64-lane DPP reduce to lane 63, then broadcast
            int bvI = __float_as_int(bv);
            unsigned bmU = bm;
            DPP_STEP(0x111)  // row_shr:1
            DPP_STEP(0x112)  // row_shr:2
            DPP_STEP(0x114)  // row_shr:4
            DPP_STEP(0x118)  // row_shr:8
            DPP_STEP(0x142)  // row_bcast:15
            DPP_STEP(0x143)  // row_bcast:31
            float delta = __int_as_float(__builtin_amdgcn_readlane(bvI, 63));
            unsigned wm = (unsigned)__builtin_amdgcn_readlane((int)bmU, 63);
            int j1 = (int)(wm >> 10);
            int pj1 = (int)(wm & 1023u) - 1;
            bool matched = (pj1 >= 0);

            // early uniform reads for next step (phase-start values; u[pj1]
            // untouched in-phase before j1's selection) — latency overlaps
            // the register update loop below
            float nui = 0.0f; float4 nG = G;
            if (matched) { nui = u[pj1]; nG = tps[pj1]; }

            // per-step updates exactly as reference (used excludes j1):
#pragma unroll
            for (int k = 0; k < 16; ++k) {
                if ((used >> k) & 1u) {
                    v[k] -= delta;
                    uacc[k] += delta;
                } else {
                    minv[k] -= delta;
                }
            }
            uu_i += delta;

            if (!matched) { jfree = j1; break; }

            // mark j1 used; snapshot its row's phase-start u into uacc
            unsigned selbit = (lane == (j1 & 63)) ? (1u << (j1 >> 6)) : 0u;
#pragma unroll
            for (int k = 0; k < 16; ++k)
                uacc[k] = ((selbit >> k) & 1u) ? nui : uacc[k];
            used |= selbit;
            j0 = j1;
            ui0 = nui;
            G = nG;
        }

        // phase epilogue: flush u and way for used columns, dummy row, jfree
#pragma unroll
        for (int k = 0; k < 16; ++k) {
            if ((used >> k) & 1u) {
                u[p_cache[k]] = uacc[k];
                way[k * 64 + lane] = (unsigned short)wayr[k];
            }
        }
        if (lane == (jfree & 63)) {
#pragma unroll
            for (int k = 0; k < 16; ++k)
                if (k == (jfree >> 6)) way[jfree] = (unsigned short)wayr[k];
        }
        if (lane == 0) u[i] = uu_i;

        // augment along predecessor chain (serial, lane 0)
        if (lane == 0) {
            int j = jfree;
            for (;;) {
                int jn = way[j];
                if (jn == QQ) { p[j] = i; break; }
                p[j] = p[jn];
                j = jn;
            }
        }
        __syncthreads();
    }

    // Output: ascending-j compaction == reference argsort(col4row).
    float* outr = out + (size_t)BB * QQ * TT + (size_t)b * TT;
    float* outc = outr + (size_t)BB * TT;
    int base = 0;
    for (int kb = 0; kb < 16; ++kb) {
        int j = kb * 64 + lane;
        int pj = p[j];
        bool a = pj >= 0;
        unsigned long long mask = __ballot(a);
        int rank = __popcll(mask & ((1ull << lane) - 1ull));
        if (a) {
            outr[base + rank] = (float)j;
            outc[base + rank] = (float)pj;
        }
        base += __popcll(mask);
    }
}

extern "C" void kernel_launch(void* const* d_in, const int* in_sizes, int n_in,
                              void* d_out, int out_size, void* d_ws, size_t ws_size,
                              hipStream_t stream) {
    const float* logits = (const float*)d_in[0];
    const float4* pp = (const float4*)d_in[1];
    const float4* tp = (const float4*)d_in[2];
    const int* labels = (const int*)d_in[3];
    float* out = (float*)d_out;

    int cls = in_sizes[0] / (BB * QQ);   // = 1 for this instance
    size_t total = (size_t)BB * QQ * TT;
    size_t diff_bytes = (size_t)in_sizes[0] * sizeof(float);

    if (ws_size >= diff_bytes) {
        float* diff = (float*)d_ws;
        int ndiff = in_sizes[0];
        diff_kernel<<<(ndiff + 255) / 256, 256, 0, stream>>>(logits, diff, ndiff);
        cost_kernel<<<(unsigned)((total + 255) / 256), 256, 0, stream>>>(
            diff, pp, tp, labels, out, cls, total);
    } else {
        cost_inline_kernel<<<(unsigned)((total + 255) / 256), 256, 0, stream>>>(
            logits, pp, tp, labels, out, cls, total);
    }

    lap_kernel<<<BB, 64, 0, stream>>>(logits, pp, tp, cls, out);
}

// Round 21
// 7465.414 us; speedup vs baseline: 2.6399x; 2.6399x over previous
//
#include <hip/hip_runtime.h>
#include <hip/hip_bf16.h>
#include <stdint.h>
#include <math.h>

#define BB 16
#define QQ 1024
#define TT 512
#define FBIG 1e9f

// ---- XLA CPU f32 tanh (Eigen generic_fast_tanh_float / GenerateVF32Tanh)
__device__ __forceinline__ float xla_tanhf(float x) {
    if (fabsf(x) < 0.0004f) return x;
    float t = fminf(fmaxf(x, -7.99881172180175781f), 7.99881172180175781f);
    float x2 = t * t;
    float p = fmaf(-2.76076847742355e-16f, x2, 2.00018790482477e-13f);
    p = fmaf(p, x2, -8.60467152213735e-11f);
    p = fmaf(p, x2, 5.12229709037114e-08f);
    p = fmaf(p, x2, 1.48572235717979e-05f);
    p = fmaf(p, x2, 6.37261928875436e-04f);
    p = fmaf(p, x2, 4.89352455891786e-03f);
    float num = t * p;
    float q = fmaf(1.19825839466702e-06f, x2, 1.18534705686654e-04f);
    q = fmaf(q, x2, 2.26843463243900e-03f);
    q = fmaf(q, x2, 4.89352518554385e-03f);
    return num / q;
}

__device__ __forceinline__ float xla_sigmoid(float x) {
    return 0.5f + 0.5f * xla_tanhf(0.5f * x);
}

// ---- XLA CPU f32 log (GenerateVF32Log, cephes)
__device__ __forceinline__ float xla_logf(float y) {
    int ix = __float_as_int(y);
    int e = ((ix >> 23) & 0xff) - 126;
    float m = __int_as_float((ix & 0x007fffff) | 0x3f000000);
    bool small = m < 0.707106781186547524f;
    float xm = m - 1.0f;
    if (small) { e -= 1; xm = xm + m; }
    float z = xm * xm;
    float p = 7.0376836292E-2f;
    p = fmaf(p, xm, -1.1514610310E-1f);
    p = fmaf(p, xm, 1.1676998740E-1f);
    p = fmaf(p, xm, -1.2420140846E-1f);
    p = fmaf(p, xm, 1.4249322787E-1f);
    p = fmaf(p, xm, -1.6668057665E-1f);
    p = fmaf(p, xm, 2.0000714765E-1f);
    p = fmaf(p, xm, -2.4999993993E-1f);
    p = fmaf(p, xm, 3.3333331174E-1f);
    float yv = (p * xm) * z;
    float fe = (float)e;
    yv = fmaf(fe, -2.12194440e-4f, yv);
    yv = yv - 0.5f * z;
    float res = xm + yv;
    res = fmaf(fe, 0.693359375f, res);
    return res;
}

__device__ __forceinline__ float xla_diff(float x) {
    float pr = xla_sigmoid(x);
    float s  = 1.0f - pr;
    float p2 = pr * pr;
    float s2 = s * s;
    float neg = (0.75f * p2) * (-xla_logf(s + 1e-8f));
    float pos = (0.25f * s2) * (-xla_logf(pr + 1e-8f));
    return pos - neg;
}

// ---- diff (focal class cost term per (b,q,c)) ----------------------------
__global__ void diff_kernel(const float* __restrict__ logits,
                            float* __restrict__ diff, int n) {
    int i = blockIdx.x * blockDim.x + threadIdx.x;
    if (i >= n) return;
    diff[i] = xla_diff(logits[i]);
}

// ---------------- cost matrix C[b][q][t] (t fastest, coalesced) -----------
__global__ void cost_kernel(const float* __restrict__ diff,
                            const float4* __restrict__ pp,
                            const float4* __restrict__ tp,
                            const int* __restrict__ labels,
                            float* __restrict__ Cout, int cls, size_t total) {
    size_t gid = (size_t)blockIdx.x * blockDim.x + threadIdx.x;
    if (gid >= total) return;
    int t = (int)(gid % TT);
    size_t bq = gid / TT;
    int q = (int)(bq % QQ);
    int b = (int)(bq / QQ);
    float4 P = pp[b * QQ + q];
    float4 G = tp[b * TT + t];
    float cp = ((fabsf(P.x - G.x) + fabsf(P.y - G.y)) + fabsf(P.z - G.z)) + fabsf(P.w - G.w);
    int lab = labels[b * TT + t];
    float cc = diff[(size_t)(b * QQ + q) * cls + lab];
    Cout[gid] = cc + cp;
}

// ---- fallback: cost with inline diff (no workspace needed) ---------------
__global__ void cost_inline_kernel(const float* __restrict__ logits,
                                   const float4* __restrict__ pp,
                                   const float4* __restrict__ tp,
                                   const int* __restrict__ labels,
                                   float* __restrict__ Cout, int cls, size_t total) {
    size_t gid = (size_t)blockIdx.x * blockDim.x + threadIdx.x;
    if (gid >= total) return;
    int t = (int)(gid % TT);
    size_t bq = gid / TT;
    int q = (int)(bq % QQ);
    int b = (int)(bq / QQ);
    float4 P = pp[b * QQ + q];
    float4 G = tp[b * TT + t];
    float cp = ((fabsf(P.x - G.x) + fabsf(P.y - G.y)) + fabsf(P.z - G.z)) + fabsf(P.w - G.w);
    int lab = labels[b * TT + t];
    float cc = xla_diff(logits[(size_t)(b * QQ + q) * cls + lab]);
    Cout[gid] = cc + cp;
}

// DPP-combine one reduction level of (value, meta) lexicographic min.
#define DPP_STEP(CTRL)                                                        \
    {                                                                         \
        int s_v = __builtin_amdgcn_update_dpp(idv, bvI, (CTRL), 0xf, 0xf, false); \
        int s_m = __builtin_amdgcn_update_dpp(-1, (int)bmU, (CTRL), 0xf, 0xf, false); \
        float fs = __int_as_float(s_v);                                       \
        float fb = __int_as_float(bvI);                                       \
        bool bt = (fs < fb) || (fs == fb && (unsigned)s_m < bmU);             \
        bvI = bt ? s_v : bvI;                                                 \
        bmU = bt ? (unsigned)s_m : bmU;                                       \
    }

// ---- LAP: 4 waves per batch (issue-width split of the proven r19 kernel).
// Wave w owns columns [w*256, w*256+256): per-wave-private v/minv/uacc/wayr
// registers (k=4). Cross-wave argmin: per-wave DPP winner -> LDS cand
// (parity double-buffer) -> one barrier -> all threads combine 4 candidates
// lexicographically by (value, meta); meta=(j<<10)|(p[j]+1) globally
// monotone in j => winner == reference first-index argmin. All f32 op
// sequences identical to r19 => bit-exact trajectory.
__global__ __launch_bounds__(256)
void lap_kernel(const float* __restrict__ logits,
                const float4* __restrict__ pp,
                const float4* __restrict__ tp,
                int cls,
                float* __restrict__ out) {
    __shared__ float u[TT];
    __shared__ float diff32[QQ];
    __shared__ float4 pps[QQ];
    __shared__ float4 tps[TT];
    __shared__ int p[QQ];
    __shared__ unsigned short way[QQ];
    __shared__ int candv[2][4];
    __shared__ unsigned candm[2][4];

    int b = blockIdx.x;
    int tid = threadIdx.x;
    int wv = tid >> 6;
    int lane = tid & 63;

    for (int j = tid; j < QQ; j += 256) {
        pps[j] = pp[b * QQ + j];
        diff32[j] = xla_diff(logits[(size_t)(b * QQ + j) * cls]);  // cls==1
        p[j] = -1;
    }
    for (int i = tid; i < TT; i += 256) {
        tps[i] = tp[b * TT + i];
        u[i] = 0.0f;
    }
    __syncthreads();

    // per-wave kernel-constant column data: LDS -> registers, once
    float dreg[4], px[4], py[4], pz[4], pw[4];
#pragma unroll
    for (int k = 0; k < 4; ++k) {
        int j = wv * 256 + k * 64 + lane;
        dreg[k] = diff32[j];
        float4 P = pps[j];
        px[k] = P.x; py[k] = P.y; pz[k] = P.z; pw[k] = P.w;
    }

    float v[4];
#pragma unroll
    for (int k = 0; k < 4; ++k) v[k] = 0.0f;

    const int idv = __float_as_int(2e9f);

    for (int i = 0; i < TT; ++i) {
        unsigned used = 0;
        float minv[4], uacc[4];
        unsigned wayr[4], meta[4];
        int p_cache[4];
#pragma unroll
        for (int k = 0; k < 4; ++k) {
            int j = wv * 256 + k * 64 + lane;
            minv[k] = FBIG;
            uacc[k] = 0.0f;
            wayr[k] = 0u;
            p_cache[k] = p[j];                       // phase-constant
            meta[k] = ((unsigned)j << 10) | (unsigned)(p_cache[k] + 1);
        }
        int j0 = QQ;            // dummy column marker (== m)
        int jfree = -1;
        float ui0 = u[i];
        float uu_i = ui0;
        float4 G = tps[i];
        int par = 0;

        for (;;) {
            float gx = G.x, gy = G.y, gz = G.z, gw = G.w;
            // relax fresh columns: cur = ((cc + cp) - u[i0]) - v[j], all f32
#pragma unroll
            for (int k = 0; k < 4; ++k) {
                float cp = ((fabsf(px[k] - gx) + fabsf(py[k] - gy))
                            + fabsf(pz[k] - gz)) + fabsf(pw[k] - gw);
                float c = dreg[k] + cp;
                float cur = (c - ui0) - v[k];
                bool fresh = !((used >> k) & 1u);
                bool upd = fresh && (cur < minv[k]);
                minv[k] = upd ? cur : minv[k];
                wayr[k] = upd ? (unsigned)j0 : wayr[k];
            }
            // lane-local argmin (linear scan, proven form), k ascending
            float bv = 2e9f;
            unsigned bm = 0xFFFFFFFFu;
#pragma unroll
            for (int k = 0; k < 4; ++k) {
                float dv = ((used >> k) & 1u) ? FBIG : minv[k];
                if (dv < bv) { bv = dv; bm = meta[k]; }
            }
            // per-wave DPP reduce to lane 63
            int bvI = __float_as_int(bv);
            unsigned bmU = bm;
            DPP_STEP(0x111)
            DPP_STEP(0x112)
            DPP_STEP(0x114)
            DPP_STEP(0x118)
            DPP_STEP(0x142)
            DPP_STEP(0x143)
            if (lane == 63) {
                candv[par][wv] = __builtin_amdgcn_readlane(bvI, 63);
                candm[par][wv] = (unsigned)__builtin_amdgcn_readlane((int)bmU, 63);
            }
            __syncthreads();
            // combine the 4 wave candidates (ascending wave order, lex-min)
            int cv = candv[par][0];
            unsigned cm = candm[par][0];
#pragma unroll
            for (int w = 1; w < 4; ++w) {
                int cv2 = candv[par][w];
                unsigned cm2 = candm[par][w];
                float f1 = __int_as_float(cv), f2 = __int_as_float(cv2);
                bool t = (f2 < f1) || (f2 == f1 && cm2 < cm);
                cv = t ? cv2 : cv;
                cm = t ? cm2 : cm;
            }
            float delta = __int_as_float(cv);
            int j1 = (int)(cm >> 10);
            int pj1 = (int)(cm & 1023u) - 1;
            bool matched = (pj1 >= 0);

            // early uniform reads (phase-start values) overlap updates below
            float nui = 0.0f; float4 nG = G;
            if (matched) { nui = u[pj1]; nG = tps[pj1]; }

            // per-step updates exactly as reference (used excludes j1):
#pragma unroll
            for (int k = 0; k < 4; ++k) {
                if ((used >> k) & 1u) {
                    v[k] -= delta;
                    uacc[k] += delta;
                } else {
                    minv[k] -= delta;
                }
            }
            uu_i += delta;
            par ^= 1;

            if (!matched) { jfree = j1; break; }

            // mark j1 used (owning wave/lane); snapshot phase-start u
            unsigned selbit = (((j1 >> 8) == wv) && (lane == (j1 & 63)))
                              ? (1u << ((j1 >> 6) & 3)) : 0u;
#pragma unroll
            for (int k = 0; k < 4; ++k)
                uacc[k] = ((selbit >> k) & 1u) ? nui : uacc[k];
            used |= selbit;
            j0 = j1;
            ui0 = nui;
            G = nG;
        }

        // phase epilogue: flush u and way for used columns, dummy row, jfree
#pragma unroll
        for (int k = 0; k < 4; ++k) {
            if ((used >> k) & 1u) {
                u[p_cache[k]] = uacc[k];
                way[wv * 256 + k * 64 + lane] = (unsigned short)wayr[k];
            }
        }
        if (((jfree >> 8) == wv) && (lane == (jfree & 63))) {
#pragma unroll
            for (int k = 0; k < 4; ++k)
                if (k == ((jfree >> 6) & 3)) way[jfree] = (unsigned short)wayr[k];
        }
        if (tid == 0) u[i] = uu_i;
        __syncthreads();

        // augment along predecessor chain (serial, thread 0)
        if (tid == 0) {
            int j = jfree;
            for (;;) {
                int jn = way[j];
                if (jn == QQ) { p[j] = i; break; }
                p[j] = p[jn];
                j = jn;
            }
        }
        __syncthreads();
    }

    // Output: ascending-j compaction == reference argsort(col4row).
    if (tid < 64) {
        float* outr = out + (size_t)BB * QQ * TT + (size_t)b * TT;
        float* outc = outr + (size_t)BB * TT;
        int base = 0;
        for (int kb = 0; kb < 16; ++kb) {
            int j = kb * 64 + lane;
            int pj = p[j];
            bool a = pj >= 0;
            unsigned long long mask = __ballot(a);
            int rank = __popcll(mask & ((1ull << lane) - 1ull));
            if (a) {
                outr[base + rank] = (float)j;
                outc[base + rank] = (float)pj;
            }
            base += __popcll(mask);
        }
    }
}

extern "C" void kernel_launch(void* const* d_in, const int* in_sizes, int n_in,
                              void* d_out, int out_size, void* d_ws, size_t ws_size,
                              hipStream_t stream) {
    const float* logits = (const float*)d_in[0];
    const float4* pp = (const float4*)d_in[1];
    const float4* tp = (const float4*)d_in[2];
    const int* labels = (const int*)d_in[3];
    float* out = (float*)d_out;

    int cls = in_sizes[0] / (BB * QQ);   // = 1 for this instance
    size_t total = (size_t)BB * QQ * TT;
    size_t diff_bytes = (size_t)in_sizes[0] * sizeof(float);

    if (ws_size >= diff_bytes) {
        float* diff = (float*)d_ws;
        int ndiff = in_sizes[0];
        diff_kernel<<<(ndiff + 255) / 256, 256, 0, stream>>>(logits, diff, ndiff);
        cost_kernel<<<(unsigned)((total + 255) / 256), 256, 0, stream>>>(
            diff, pp, tp, labels, out, cls, total);
    } else {
        cost_inline_kernel<<<(unsigned)((total + 255) / 256), 256, 0, stream>>>(
            logits, pp, tp, labels, out, cls, total);
    }

    lap_kernel<<<BB, 256, 0, stream>>>(logits, pp, tp, cls, out);
}